// Round 14
// baseline (272.248 us; speedup 1.0000x reference)
//
#include <hip/hip_runtime.h>

#define D 64
#define SH 8   // XCD shards

typedef unsigned long long u64;
typedef unsigned short u16;
typedef unsigned char u8;

__device__ __forceinline__ float uaf(unsigned u) { return __uint_as_float(u); }

__device__ __forceinline__ unsigned pkbf(float lo, float hi) {
    unsigned ul = __float_as_uint(lo);
    unsigned uh = __float_as_uint(hi);
    ul = (ul + 0x7fffu + ((ul >> 16) & 1u)) >> 16;
    uh = (uh + 0x7fffu + ((uh >> 16) & 1u)) & 0xffff0000u;
    return ul | uh;
}

__device__ __forceinline__ u64 mkpack(float e0, float e1) {
    u64 q0 = (u64)(unsigned)(e0 * 65536.0f);
    u64 q1 = (u64)(unsigned)(e1 * 65536.0f);
    return (1ULL << 54) | (q0 << 27) | q1;
}

// ---------------------------------------------------------------------------
// K-1: f32 -> bf16 conversion (8 floats/thread)
// ---------------------------------------------------------------------------
__global__ __launch_bounds__(256) void k_cvt(
    const float4* __restrict__ X4, uint4* __restrict__ Xb4, int total)
{
    int i = blockIdx.x * 256 + threadIdx.x;
    if (i >= total) return;
    float4 a = X4[i * 2], b = X4[i * 2 + 1];
    uint4 o;
    o.x = pkbf(a.x, a.y); o.y = pkbf(a.z, a.w);
    o.z = pkbf(b.x, b.y); o.w = pkbf(b.z, b.w);
    Xb4[i] = o;
}

// ---------------------------------------------------------------------------
// K0: Ttw[which][j] = sum_k tw[a][k] * W[base+k][j]  for both layers
// ---------------------------------------------------------------------------
__global__ __launch_bounds__(256) void k_ttw(
    const float* __restrict__ tw1, const float* __restrict__ W1, float* __restrict__ T1,
    const float* __restrict__ tw2, const float* __restrict__ W2, float* __restrict__ T2)
{
    const float* tw = blockIdx.x ? tw2 : tw1;
    const float* W  = blockIdx.x ? W2  : W1;
    float*       T  = blockIdx.x ? T2  : T1;
    int t = threadIdx.x;
    int j = t & 63;
    int which = t >> 6;
    int a = which & 1;
    int base = (which < 2) ? 64 : 192;
    float s = 0.f;
    #pragma unroll 8
    for (int k = 0; k < 64; ++k)
        s += tw[a * 64 + k] * W[(base + k) * 64 + j];
    T[which * 64 + j] = s;
}

// ---------------------------------------------------------------------------
// K1: per-(shard,node) packed count+label atomics, 4 edges/thread.
// ~22 scattered-atomic-ops/ns is a measured device ceiling (r3/r11/r12) ->
// 1.6M ops = ~73us floor; this kernel is AT the floor. [cnt:10|q0:27|q1:27]
// ---------------------------------------------------------------------------
__global__ __launch_bounds__(256) void k_count(
    const int* __restrict__ row, const int* __restrict__ col,
    const float* __restrict__ el,
    u64* __restrict__ packR, u64* __restrict__ packC,
    u8* __restrict__ rankR, u8* __restrict__ rankC, int E, int N, int SH_SZ)
{
    int s = blockIdx.x & (SH - 1);
    int j = blockIdx.x >> 3;
    int ebase = s * SH_SZ;
    int ssz = min(SH_SZ, E - ebase);
    int i0 = (j * 256 + threadIdx.x) * 4;
    if (i0 >= ssz) return;
    int e0 = ebase + i0;
    u64* pR = packR + (size_t)s * N;
    u64* pC = packC + (size_t)s * N;
    if (i0 + 4 <= ssz) {
        int4 rr = *(const int4*)(row + e0);
        int4 cc = *(const int4*)(col + e0);
        float4 l0 = *(const float4*)(el + 2 * e0);
        float4 l1 = *(const float4*)(el + 2 * e0 + 4);
        u64 p0 = mkpack(l0.x, l0.y), p1 = mkpack(l0.z, l0.w);
        u64 p2 = mkpack(l1.x, l1.y), p3 = mkpack(l1.z, l1.w);
        u64 oR0 = atomicAdd(&pR[rr.x], p0);
        u64 oR1 = atomicAdd(&pR[rr.y], p1);
        u64 oR2 = atomicAdd(&pR[rr.z], p2);
        u64 oR3 = atomicAdd(&pR[rr.w], p3);
        u64 oC0 = atomicAdd(&pC[cc.x], p0);
        u64 oC1 = atomicAdd(&pC[cc.y], p1);
        u64 oC2 = atomicAdd(&pC[cc.z], p2);
        u64 oC3 = atomicAdd(&pC[cc.w], p3);
        *(uchar4*)(rankR + e0) = make_uchar4(
            (u8)(oR0 >> 54), (u8)(oR1 >> 54), (u8)(oR2 >> 54), (u8)(oR3 >> 54));
        *(uchar4*)(rankC + e0) = make_uchar4(
            (u8)(oC0 >> 54), (u8)(oC1 >> 54), (u8)(oC2 >> 54), (u8)(oC3 >> 54));
    } else {
        int m = ssz - i0;
        for (int q = 0; q < m; ++q) {
            int e = e0 + q;
            float2 lab = ((const float2*)el)[e];
            u64 p = mkpack(lab.x, lab.y);
            rankR[e] = (u8)(atomicAdd(&pR[row[e]], p) >> 54);
            rankC[e] = (u8)(atomicAdd(&pC[col[e]], p) >> 54);
        }
    }
}

// ---------------------------------------------------------------------------
// K2: per-shard segment allocation (16 scans) + compact CSR offsets (2 more
// scans). ONE parallel atomic round per block on 18 line-padded counters.
// curX[s][n] = absolute START of (shard,node) segment (never advanced).
// ---------------------------------------------------------------------------
__global__ __launch_bounds__(256) void k_prep(
    const u64* __restrict__ packR, const u64* __restrict__ packC,
    int* __restrict__ curR, int* __restrict__ curC,
    u64* __restrict__ degpackR, u64* __restrict__ degpackC,
    int* __restrict__ off_row, int* __restrict__ off_col,
    float* __restrict__ stats, int* __restrict__ gcur, int N, int SH_SZ)
{
    __shared__ int lds_tot[4][18];
    __shared__ int lds_base[4][18];

    int n = blockIdx.x * 256 + threadIdx.x;
    int lane = threadIdx.x & 63;
    int wv = threadIdx.x >> 6;
    const u64 LOW54 = (1ULL << 54) - 1;
    int cr[SH], cc[SH], psR[SH], psC[SH];
    u64 TR = 0, TC = 0;
    #pragma unroll
    for (int s = 0; s < SH; ++s) {
        u64 pR = (n < N) ? packR[(size_t)s * N + n] : 0;
        u64 pC = (n < N) ? packC[(size_t)s * N + n] : 0;
        cr[s] = (int)(pR >> 54); TR += pR & LOW54;
        cc[s] = (int)(pC >> 54); TC += pC & LOW54;
    }
    int tr = 0, tc = 0;
    #pragma unroll
    for (int s = 0; s < SH; ++s) { tr += cr[s]; tc += cc[s]; }

    #pragma unroll
    for (int s = 0; s < SH; ++s) {
        int ps = cr[s];
        #pragma unroll
        for (int d2 = 1; d2 < 64; d2 <<= 1) { int t2 = __shfl_up(ps, d2); if (lane >= d2) ps += t2; }
        psR[s] = ps;
        int ps2 = cc[s];
        #pragma unroll
        for (int d2 = 1; d2 < 64; d2 <<= 1) { int t2 = __shfl_up(ps2, d2); if (lane >= d2) ps2 += t2; }
        psC[s] = ps2;
        if (lane == 63) { lds_tot[wv][s] = ps; lds_tot[wv][8 + s] = ps2; }
    }
    int psT = tr, psU = tc;
    #pragma unroll
    for (int d2 = 1; d2 < 64; d2 <<= 1) {
        int t2 = __shfl_up(psT, d2);
        int t3 = __shfl_up(psU, d2);
        if (lane >= d2) { psT += t2; psU += t3; }
    }
    if (lane == 63) { lds_tot[wv][16] = psT; lds_tot[wv][17] = psU; }
    __syncthreads();
    if (wv == 0 && lane < 18) {
        int t0 = lds_tot[0][lane], t1 = lds_tot[1][lane],
            t2 = lds_tot[2][lane], t3 = lds_tot[3][lane];
        int gb = atomicAdd(&gcur[lane * 32], t0 + t1 + t2 + t3);
        lds_base[0][lane] = gb;
        lds_base[1][lane] = gb + t0;
        lds_base[2][lane] = gb + t0 + t1;
        lds_base[3][lane] = gb + t0 + t1 + t2;
    }
    __syncthreads();

    if (n < N) {
        u64 dpR = 0, dpC = 0;
        #pragma unroll
        for (int s = 0; s < SH; ++s) {
            curR[(size_t)s * N + n] = s * SH_SZ + lds_base[wv][s]     + psR[s] - cr[s];
            curC[(size_t)s * N + n] = s * SH_SZ + lds_base[wv][8 + s] + psC[s] - cc[s];
            dpR |= ((u64)cr[s]) << (8 * s);
            dpC |= ((u64)cc[s]) << (8 * s);
        }
        degpackR[n] = dpR;
        degpackC[n] = dpC;
        off_row[n] = lds_base[wv][16] + psT - tr;
        off_col[n] = lds_base[wv][17] + psU - tc;
        const u64 M27 = (1ULL << 27) - 1;
        const float qs = 1.0f / 65536.0f;
        float sr0 = (float)((TR >> 27) & M27) * qs;
        float sr1 = (float)(TR & M27) * qs;
        float sc0 = (float)((TC >> 27) & M27) * qs;
        float sc1 = (float)(TC & M27) * qs;
        float ir = 1.0f / fmaxf((float)tr, 1.0f);
        float ic = 1.0f / fmaxf((float)tc, 1.0f);
        float* sN = stats + (size_t)n * 8;
        sN[0] = ir;        sN[1] = ic;
        sN[2] = sr0 * ir;  sN[3] = sr1 * ir;
        sN[4] = sc0 * ic;  sN[5] = sc1 * ic;
        sN[6] = (float)tr; sN[7] = (float)tc;
    }
}

// ---------------------------------------------------------------------------
// K3: ATOMIC-FREE sharded fill, 4 edges/thread.
// ---------------------------------------------------------------------------
__global__ __launch_bounds__(256) void k_fill(
    const int* __restrict__ row, const int* __restrict__ col,
    const u8* __restrict__ rankR, const u8* __restrict__ rankC,
    const int* __restrict__ curR, const int* __restrict__ curC,
    int* __restrict__ stageR, int* __restrict__ stageC, int E, int N, int SH_SZ)
{
    int s = blockIdx.x & (SH - 1);
    int j = blockIdx.x >> 3;
    int ebase = s * SH_SZ;
    int ssz = min(SH_SZ, E - ebase);
    int i0 = (j * 256 + threadIdx.x) * 4;
    if (i0 >= ssz) return;
    int e0 = ebase + i0;
    const int* cR = curR + (size_t)s * N;
    const int* cC = curC + (size_t)s * N;
    if (i0 + 4 <= ssz) {
        int4 rr = *(const int4*)(row + e0);
        int4 cc = *(const int4*)(col + e0);
        uchar4 kR = *(const uchar4*)(rankR + e0);
        uchar4 kC = *(const uchar4*)(rankC + e0);
        int aR0 = cR[rr.x], aR1 = cR[rr.y], aR2 = cR[rr.z], aR3 = cR[rr.w];
        int aC0 = cC[cc.x], aC1 = cC[cc.y], aC2 = cC[cc.z], aC3 = cC[cc.w];
        stageR[aR0 + kR.x] = cc.x;
        stageR[aR1 + kR.y] = cc.y;
        stageR[aR2 + kR.z] = cc.z;
        stageR[aR3 + kR.w] = cc.w;
        stageC[aC0 + kC.x] = rr.x;
        stageC[aC1 + kC.y] = rr.y;
        stageC[aC2 + kC.z] = rr.z;
        stageC[aC3 + kC.w] = rr.w;
    } else {
        int m = ssz - i0;
        for (int q = 0; q < m; ++q) {
            int e = e0 + q;
            int r = row[e], c = col[e];
            stageR[cR[r] + rankR[e]] = c;
            stageC[cC[c] + rankC[e]] = r;
        }
    }
}

// ---------------------------------------------------------------------------
// K3.5: compact the 8 sharded segments per node into a true CSR.
// cur = segment START -> src = cur[s] + (k - p[s]).
// ---------------------------------------------------------------------------
__global__ __launch_bounds__(256) void k_reorder(
    const int* __restrict__ stageR, const int* __restrict__ stageC,
    const int* __restrict__ curR, const int* __restrict__ curC,
    const u64* __restrict__ degpackR, const u64* __restrict__ degpackC,
    const int* __restrict__ off_row, const int* __restrict__ off_col,
    int* __restrict__ nbrR, int* __restrict__ nbrC, int N)
{
    int n = blockIdx.x * 4 + (threadIdx.x >> 6);
    if (n >= N) return;
    int lane = threadIdx.x & 63;

    {
        u64 dp = degpackR[n];
        int d[SH], p[SH], st[SH];
        #pragma unroll
        for (int s = 0; s < SH; ++s) d[s] = (int)((dp >> (8 * s)) & 255);
        p[0] = 0;
        #pragma unroll
        for (int s = 1; s < SH; ++s) p[s] = p[s - 1] + d[s - 1];
        int deg = p[SH - 1] + d[SH - 1];
        #pragma unroll
        for (int s = 0; s < SH; ++s)
            st[s] = curR[(size_t)s * N + n] - p[s];
        int base = off_row[n];
        for (int k = lane; k < deg; k += 64) {
            int src = st[0] + k;
            #pragma unroll
            for (int s = 1; s < SH; ++s)
                src = (k >= p[s]) ? st[s] + k : src;
            nbrR[base + k] = stageR[src];
        }
    }
    {
        u64 dp = degpackC[n];
        int d[SH], p[SH], st[SH];
        #pragma unroll
        for (int s = 0; s < SH; ++s) d[s] = (int)((dp >> (8 * s)) & 255);
        p[0] = 0;
        #pragma unroll
        for (int s = 1; s < SH; ++s) p[s] = p[s - 1] + d[s - 1];
        int deg = p[SH - 1] + d[SH - 1];
        #pragma unroll
        for (int s = 0; s < SH; ++s)
            st[s] = curC[(size_t)s * N + n] - p[s];
        int base = off_col[n];
        for (int k = lane; k < deg; k += 64) {
            int src = st[0] + k;
            #pragma unroll
            for (int s = 1; s < SH; ++s)
                src = (k >= p[s]) ? st[s] + k : src;
            nbrC[base + k] = stageC[src];
        }
    }
}

// ---------------------------------------------------------------------------
// K4: fused layer, compact CSR + bf16. 512 threads, 16 nodes/block, 2 nodes/
// wave. NEW: BOTH nodes' gathers merged into ONE loop -> 8 independent
// idx->row load chains per iteration (2 nodes x 2 sides x 4-neighbor step).
// __launch_bounds__(512,8) pins VGPR <=64 so 8 waves/SIMD survive.
// Ws staged first with one barrier; waves free-run after it.
// ---------------------------------------------------------------------------
__global__ __launch_bounds__(512, 8) void k_layer(
    const u16* __restrict__ xb,
    const int* __restrict__ off_row, const int* __restrict__ off_col,
    const int* __restrict__ nbrR, const int* __restrict__ nbrC,
    const float* __restrict__ stats,
    const float* __restrict__ Ttw,   // [4][64]
    const float* __restrict__ W,     // [256][64]
    const float* __restrict__ b,     // [64]
    u16* __restrict__ yb, float* __restrict__ yf, int N)
{
    __shared__ float4 hs4[16][32];
    __shared__ float  Ws[128 * 64];

    const uint2* xb2 = (const uint2*)xb;

    int t    = threadIdx.x;
    int lane = t & 63;
    int wv   = t >> 6;
    int c4   = lane & 15;
    int grp  = lane >> 4;
    int base = blockIdx.x * 16;

    // ---- stage W (rows 0..63 and 128..191) FIRST; single barrier ----
    #pragma unroll
    for (int i = 0; i < 16; ++i) {
        int L = i * 512 + t;
        Ws[L] = W[L + ((L < 4096) ? 0 : 4096)];
    }
    __syncthreads();

    int n0 = base + wv * 2;
    int n1 = n0 + 1;

    float4 sA0 = make_float4(0.f,0.f,0.f,0.f), sB0 = make_float4(0.f,0.f,0.f,0.f);
    float4 sA1 = make_float4(0.f,0.f,0.f,0.f), sB1 = make_float4(0.f,0.f,0.f,0.f);
    int dR0 = 0, dC0 = 0, dR1 = 0, dC1 = 0;
    int sR0 = 0, sC0 = 0, sR1 = 0, sC1 = 0;
    if (n0 < N) {
        const float4* st = (const float4*)(stats + (size_t)n0 * 8);
        sA0 = st[0]; sB0 = st[1];
        dR0 = (int)sB0.z; dC0 = (int)sB0.w;
        sR0 = off_row[n0]; sC0 = off_col[n0];
    }
    if (n1 < N) {
        const float4* st = (const float4*)(stats + (size_t)n1 * 8);
        sA1 = st[0]; sB1 = st[1];
        dR1 = (int)sB1.z; dC1 = (int)sB1.w;
        sR1 = off_row[n1]; sC1 = off_col[n1];
    }

    float4 aR0 = make_float4(0.f,0.f,0.f,0.f), aC0 = make_float4(0.f,0.f,0.f,0.f);
    float4 aR1 = make_float4(0.f,0.f,0.f,0.f), aC1 = make_float4(0.f,0.f,0.f,0.f);

    int m = max(max(dR0, dC0), max(dR1, dC1));
    for (int k = 0; k < m; k += 4) {
        int kk = k + grp;
        bool pR0 = kk < dR0, pC0 = kk < dC0;
        bool pR1 = kk < dR1, pC1 = kk < dC1;
        // 4 independent index loads
        int iR0 = nbrR[pR0 ? sR0 + kk : 0];
        int iC0 = nbrC[pC0 ? sC0 + kk : 0];
        int iR1 = nbrR[pR1 ? sR1 + kk : 0];
        int iC1 = nbrC[pC1 ? sC1 + kk : 0];
        // 4 independent row loads
        uint2 vR0 = xb2[(size_t)iR0 * 16 + c4];
        uint2 vC0 = xb2[(size_t)iC0 * 16 + c4];
        uint2 vR1 = xb2[(size_t)iR1 * 16 + c4];
        uint2 vC1 = xb2[(size_t)iC1 * 16 + c4];
        if (pR0) {
            aR0.x += uaf(vR0.x << 16); aR0.y += uaf(vR0.x & 0xffff0000u);
            aR0.z += uaf(vR0.y << 16); aR0.w += uaf(vR0.y & 0xffff0000u);
        }
        if (pC0) {
            aC0.x += uaf(vC0.x << 16); aC0.y += uaf(vC0.x & 0xffff0000u);
            aC0.z += uaf(vC0.y << 16); aC0.w += uaf(vC0.y & 0xffff0000u);
        }
        if (pR1) {
            aR1.x += uaf(vR1.x << 16); aR1.y += uaf(vR1.x & 0xffff0000u);
            aR1.z += uaf(vR1.y << 16); aR1.w += uaf(vR1.y & 0xffff0000u);
        }
        if (pC1) {
            aC1.x += uaf(vC1.x << 16); aC1.y += uaf(vC1.x & 0xffff0000u);
            aC1.z += uaf(vC1.y << 16); aC1.w += uaf(vC1.y & 0xffff0000u);
        }
    }

    // cross-group butterflies (result valid in all lanes)
    #pragma unroll
    for (int o = 16; o < 64; o <<= 1) {
        aR0.x += __shfl_xor(aR0.x, o); aR0.y += __shfl_xor(aR0.y, o);
        aR0.z += __shfl_xor(aR0.z, o); aR0.w += __shfl_xor(aR0.w, o);
        aC0.x += __shfl_xor(aC0.x, o); aC0.y += __shfl_xor(aC0.y, o);
        aC0.z += __shfl_xor(aC0.z, o); aC0.w += __shfl_xor(aC0.w, o);
        aR1.x += __shfl_xor(aR1.x, o); aR1.y += __shfl_xor(aR1.y, o);
        aR1.z += __shfl_xor(aR1.z, o); aR1.w += __shfl_xor(aR1.w, o);
        aC1.x += __shfl_xor(aC1.x, o); aC1.y += __shfl_xor(aC1.y, o);
        aC1.z += __shfl_xor(aC1.z, o); aC1.w += __shfl_xor(aC1.w, o);
    }
    if (grp == 0) {
        int loc0 = wv * 2, loc1 = wv * 2 + 1;
        float ir0 = sA0.x, ic0 = sA0.y, ir1 = sA1.x, ic1 = sA1.y;
        hs4[loc0][c4]      = make_float4(aR0.x*ir0, aR0.y*ir0, aR0.z*ir0, aR0.w*ir0);
        hs4[loc0][16 + c4] = make_float4(aC0.x*ic0, aC0.y*ic0, aC0.z*ic0, aC0.w*ic0);
        hs4[loc1][c4]      = make_float4(aR1.x*ir1, aR1.y*ir1, aR1.z*ir1, aR1.w*ir1);
        hs4[loc1][16 + c4] = make_float4(aC1.x*ic1, aC1.y*ic1, aC1.z*ic1, aC1.w*ic1);
    }

    // Phase B: per-wave, reads only this wave's hs rows (no barrier needed)
    const float* hsf = (const float*)hs4;
    int r0 = (wv * 2) * 128, r1 = r0 + 128;
    float a0 = 0.f, a1 = 0.f;
    #pragma unroll 8
    for (int j = 0; j < 128; ++j) {
        float wj = Ws[j * 64 + lane];
        a0 += hsf[r0 + j] * wj;
        a1 += hsf[r1 + j] * wj;
    }

    float tR0 = Ttw[lane],       tR1 = Ttw[64 + lane];
    float tC0 = Ttw[128 + lane], tC1 = Ttw[192 + lane];
    float bias = b[lane];
    {
        if (n0 < N) {
            float v = a0 + sA0.z * tR0 + sA0.w * tR1
                         + sB0.x * tC0 + sB0.y * tC1 + bias;
            v = fmaxf(v, 0.0f);
            if (yf) {
                yf[(size_t)n0 * D + lane] = v;
            } else {
                unsigned u = __float_as_uint(v);
                yb[(size_t)n0 * D + lane] = (u16)((u + 0x7fffu + ((u >> 16) & 1u)) >> 16);
            }
        }
        if (n1 < N) {
            float v = a1 + sA1.z * tR0 + sA1.w * tR1
                         + sB1.x * tC0 + sB1.y * tC1 + bias;
            v = fmaxf(v, 0.0f);
            if (yf) {
                yf[(size_t)n1 * D + lane] = v;
            } else {
                unsigned u = __float_as_uint(v);
                yb[(size_t)n1 * D + lane] = (u16)((u + 0x7fffu + ((u >> 16) & 1u)) >> 16);
            }
        }
    }
}

// ---------------------------------------------------------------------------
extern "C" void kernel_launch(void* const* d_in, const int* in_sizes, int n_in,
                              void* d_out, int out_size, void* d_ws, size_t ws_size,
                              hipStream_t stream)
{
    const float* X   = (const float*)d_in[0];
    const int*   ei  = (const int*)  d_in[1];
    const float* el  = (const float*)d_in[2];
    const float* w1  = (const float*)d_in[3];
    const float* tw1 = (const float*)d_in[4];
    const float* b1  = (const float*)d_in[5];
    const float* w2  = (const float*)d_in[6];
    const float* tw2 = (const float*)d_in[7];
    const float* b2  = (const float*)d_in[8];
    float* out = (float*)d_out;

    int N = in_sizes[0] / D;     // 50000
    int E = in_sizes[1] / 2;     // 800000
    const int* row = ei;
    const int* col = ei + E;
    int SH_SZ = (((E + SH - 1) / SH) + 3) & ~3;   // multiple of 4 for int4 loads

    // Workspace (~25.6 MiB). pack -> stage CSR -> h1 bf16 share a region.
    size_t packBytes = (size_t)2 * SH * N * sizeof(u64);
    size_t stageBytes = (size_t)2 * (size_t)SH * SH_SZ * sizeof(int);
    size_t h1Bytes = (size_t)64 * N * sizeof(u16);
    if (stageBytes > packBytes) packBytes = stageBytes;
    if (h1Bytes > packBytes) packBytes = h1Bytes;

    char* wsb = (char*)d_ws;
    u64*   packR    = (u64*)wsb;                        // SH*N u64 (zeroed)
    u64*   packC    = packR + (size_t)SH * N;           // SH*N u64 (zeroed)
    int*   stageR   = (int*)wsb;                        // SH*SH_SZ ints (aliases pack)
    int*   stageC   = stageR + (size_t)SH * SH_SZ;      // SH*SH_SZ ints
    u16*   h1b      = (u16*)wsb;                        // 64N bf16 (aliases stage)
    int*   gcur     = (int*)(wsb + packBytes);          // 1024 ints line-padded (zeroed)
    int*   curR     = gcur + 1024;                      // SH*N
    int*   curC     = curR + (size_t)SH * N;            // SH*N
    u64*   degpackR = (u64*)(curC + (size_t)SH * N);    // N
    u64*   degpackC = degpackR + N;                     // N
    int*   off_row  = (int*)(degpackC + N);             // N
    int*   off_col  = off_row + N;                      // N
    float* stats    = (float*)(off_col + N);            // 8N
    float* Ttw1     = stats + (size_t)8 * N;            // 256
    float* Ttw2     = Ttw1 + 256;                       // 256
    int*   nbrR     = (int*)(Ttw2 + 256);               // E
    int*   nbrC     = nbrR + E;                         // E
    u16*   Xb       = (u16*)(nbrC + E);                 // 64N bf16
    u8*    rankR    = (u8*)(Xb + (size_t)64 * N);       // E
    u8*    rankC    = rankR + E;                        // E

    (void)hipMemsetAsync(packR, 0, (size_t)2 * SH * N * sizeof(u64), stream);
    (void)hipMemsetAsync(gcur, 0, 1024 * sizeof(int), stream);

    k_cvt<<<(N * 8 + 255) / 256, 256, 0, stream>>>((const float4*)X, (uint4*)Xb, N * 8);
    k_ttw<<<2, 256, 0, stream>>>(tw1, w1, Ttw1, tw2, w2, Ttw2);

    int SB4 = SH * ((SH_SZ + 1023) / 1024);
    int NB = (N + 255) / 256;
    int RB = (N + 3) / 4;
    int LB = (N + 15) / 16;

    k_count<<<SB4, 256, 0, stream>>>(row, col, el, packR, packC,
                                     rankR, rankC, E, N, SH_SZ);
    k_prep<<<NB, 256, 0, stream>>>(packR, packC, curR, curC,
                                   degpackR, degpackC, off_row, off_col,
                                   stats, gcur, N, SH_SZ);
    k_fill<<<SB4, 256, 0, stream>>>(row, col, rankR, rankC, curR, curC,
                                    stageR, stageC, E, N, SH_SZ);
    k_reorder<<<RB, 256, 0, stream>>>(stageR, stageC, curR, curC,
                                      degpackR, degpackC, off_row, off_col,
                                      nbrR, nbrC, N);

    // layer 1: Xb -> h1b (bf16, aliases dead stage region); layer 2 -> out f32
    k_layer<<<LB, 512, 0, stream>>>(Xb, off_row, off_col, nbrR, nbrC, stats,
                                    Ttw1, w1, b1, h1b, nullptr, N);
    k_layer<<<LB, 512, 0, stream>>>(h1b, off_row, off_col, nbrR, nbrC, stats,
                                    Ttw2, w2, b2, nullptr, out, N);
}

// Round 15
// 247.512 us; speedup vs baseline: 1.0999x; 1.0999x over previous
//
#include <hip/hip_runtime.h>

#define D 64
#define SH 8   // XCD shards

typedef unsigned long long u64;
typedef unsigned short u16;
typedef unsigned char u8;

__device__ __forceinline__ float uaf(unsigned u) { return __uint_as_float(u); }

__device__ __forceinline__ unsigned pkbf(float lo, float hi) {
    unsigned ul = __float_as_uint(lo);
    unsigned uh = __float_as_uint(hi);
    ul = (ul + 0x7fffu + ((ul >> 16) & 1u)) >> 16;
    uh = (uh + 0x7fffu + ((uh >> 16) & 1u)) & 0xffff0000u;
    return ul | uh;
}

__device__ __forceinline__ u64 mkpack(float e0, float e1) {
    u64 q0 = (u64)(unsigned)(e0 * 65536.0f);
    u64 q1 = (u64)(unsigned)(e1 * 65536.0f);
    return (1ULL << 54) | (q0 << 27) | q1;
}

// ---------------------------------------------------------------------------
// K-1: f32 -> bf16 conversion (8 floats/thread)
// ---------------------------------------------------------------------------
__global__ __launch_bounds__(256) void k_cvt(
    const float4* __restrict__ X4, uint4* __restrict__ Xb4, int total)
{
    int i = blockIdx.x * 256 + threadIdx.x;
    if (i >= total) return;
    float4 a = X4[i * 2], b = X4[i * 2 + 1];
    uint4 o;
    o.x = pkbf(a.x, a.y); o.y = pkbf(a.z, a.w);
    o.z = pkbf(b.x, b.y); o.w = pkbf(b.z, b.w);
    Xb4[i] = o;
}

// ---------------------------------------------------------------------------
// K0: Ttw[which][j] = sum_k tw[a][k] * W[base+k][j]  for both layers
// ---------------------------------------------------------------------------
__global__ __launch_bounds__(256) void k_ttw(
    const float* __restrict__ tw1, const float* __restrict__ W1, float* __restrict__ T1,
    const float* __restrict__ tw2, const float* __restrict__ W2, float* __restrict__ T2)
{
    const float* tw = blockIdx.x ? tw2 : tw1;
    const float* W  = blockIdx.x ? W2  : W1;
    float*       T  = blockIdx.x ? T2  : T1;
    int t = threadIdx.x;
    int j = t & 63;
    int which = t >> 6;
    int a = which & 1;
    int base = (which < 2) ? 64 : 192;
    float s = 0.f;
    #pragma unroll 8
    for (int k = 0; k < 64; ++k)
        s += tw[a * 64 + k] * W[(base + k) * 64 + j];
    T[which * 64 + j] = s;
}

// ---------------------------------------------------------------------------
// K1: per-(shard,node) packed count+label atomics, 4 edges/thread.
// ~22 scattered-atomic-ops/ns is a measured device ceiling (r3/r11/r12) ->
// 1.6M ops = ~73us floor; this kernel is AT the floor. [cnt:10|q0:27|q1:27]
// ---------------------------------------------------------------------------
__global__ __launch_bounds__(256) void k_count(
    const int* __restrict__ row, const int* __restrict__ col,
    const float* __restrict__ el,
    u64* __restrict__ packR, u64* __restrict__ packC,
    u8* __restrict__ rankR, u8* __restrict__ rankC, int E, int N, int SH_SZ)
{
    int s = blockIdx.x & (SH - 1);
    int j = blockIdx.x >> 3;
    int ebase = s * SH_SZ;
    int ssz = min(SH_SZ, E - ebase);
    int i0 = (j * 256 + threadIdx.x) * 4;
    if (i0 >= ssz) return;
    int e0 = ebase + i0;
    u64* pR = packR + (size_t)s * N;
    u64* pC = packC + (size_t)s * N;
    if (i0 + 4 <= ssz) {
        int4 rr = *(const int4*)(row + e0);
        int4 cc = *(const int4*)(col + e0);
        float4 l0 = *(const float4*)(el + 2 * e0);
        float4 l1 = *(const float4*)(el + 2 * e0 + 4);
        u64 p0 = mkpack(l0.x, l0.y), p1 = mkpack(l0.z, l0.w);
        u64 p2 = mkpack(l1.x, l1.y), p3 = mkpack(l1.z, l1.w);
        u64 oR0 = atomicAdd(&pR[rr.x], p0);
        u64 oR1 = atomicAdd(&pR[rr.y], p1);
        u64 oR2 = atomicAdd(&pR[rr.z], p2);
        u64 oR3 = atomicAdd(&pR[rr.w], p3);
        u64 oC0 = atomicAdd(&pC[cc.x], p0);
        u64 oC1 = atomicAdd(&pC[cc.y], p1);
        u64 oC2 = atomicAdd(&pC[cc.z], p2);
        u64 oC3 = atomicAdd(&pC[cc.w], p3);
        *(uchar4*)(rankR + e0) = make_uchar4(
            (u8)(oR0 >> 54), (u8)(oR1 >> 54), (u8)(oR2 >> 54), (u8)(oR3 >> 54));
        *(uchar4*)(rankC + e0) = make_uchar4(
            (u8)(oC0 >> 54), (u8)(oC1 >> 54), (u8)(oC2 >> 54), (u8)(oC3 >> 54));
    } else {
        int m = ssz - i0;
        for (int q = 0; q < m; ++q) {
            int e = e0 + q;
            float2 lab = ((const float2*)el)[e];
            u64 p = mkpack(lab.x, lab.y);
            rankR[e] = (u8)(atomicAdd(&pR[row[e]], p) >> 54);
            rankC[e] = (u8)(atomicAdd(&pC[col[e]], p) >> 54);
        }
    }
}

// ---------------------------------------------------------------------------
// K2: per-shard segment allocation (16 scans) + compact CSR offsets (2 more
// scans). ONE parallel atomic round per block on 18 line-padded counters.
// curX[s][n] = absolute START of (shard,node) segment (never advanced).
// ---------------------------------------------------------------------------
__global__ __launch_bounds__(256) void k_prep(
    const u64* __restrict__ packR, const u64* __restrict__ packC,
    int* __restrict__ curR, int* __restrict__ curC,
    u64* __restrict__ degpackR, u64* __restrict__ degpackC,
    int* __restrict__ off_row, int* __restrict__ off_col,
    float* __restrict__ stats, int* __restrict__ gcur, int N, int SH_SZ)
{
    __shared__ int lds_tot[4][18];
    __shared__ int lds_base[4][18];

    int n = blockIdx.x * 256 + threadIdx.x;
    int lane = threadIdx.x & 63;
    int wv = threadIdx.x >> 6;
    const u64 LOW54 = (1ULL << 54) - 1;
    int cr[SH], cc[SH], psR[SH], psC[SH];
    u64 TR = 0, TC = 0;
    #pragma unroll
    for (int s = 0; s < SH; ++s) {
        u64 pR = (n < N) ? packR[(size_t)s * N + n] : 0;
        u64 pC = (n < N) ? packC[(size_t)s * N + n] : 0;
        cr[s] = (int)(pR >> 54); TR += pR & LOW54;
        cc[s] = (int)(pC >> 54); TC += pC & LOW54;
    }
    int tr = 0, tc = 0;
    #pragma unroll
    for (int s = 0; s < SH; ++s) { tr += cr[s]; tc += cc[s]; }

    #pragma unroll
    for (int s = 0; s < SH; ++s) {
        int ps = cr[s];
        #pragma unroll
        for (int d2 = 1; d2 < 64; d2 <<= 1) { int t2 = __shfl_up(ps, d2); if (lane >= d2) ps += t2; }
        psR[s] = ps;
        int ps2 = cc[s];
        #pragma unroll
        for (int d2 = 1; d2 < 64; d2 <<= 1) { int t2 = __shfl_up(ps2, d2); if (lane >= d2) ps2 += t2; }
        psC[s] = ps2;
        if (lane == 63) { lds_tot[wv][s] = ps; lds_tot[wv][8 + s] = ps2; }
    }
    int psT = tr, psU = tc;
    #pragma unroll
    for (int d2 = 1; d2 < 64; d2 <<= 1) {
        int t2 = __shfl_up(psT, d2);
        int t3 = __shfl_up(psU, d2);
        if (lane >= d2) { psT += t2; psU += t3; }
    }
    if (lane == 63) { lds_tot[wv][16] = psT; lds_tot[wv][17] = psU; }
    __syncthreads();
    if (wv == 0 && lane < 18) {
        int t0 = lds_tot[0][lane], t1 = lds_tot[1][lane],
            t2 = lds_tot[2][lane], t3 = lds_tot[3][lane];
        int gb = atomicAdd(&gcur[lane * 32], t0 + t1 + t2 + t3);
        lds_base[0][lane] = gb;
        lds_base[1][lane] = gb + t0;
        lds_base[2][lane] = gb + t0 + t1;
        lds_base[3][lane] = gb + t0 + t1 + t2;
    }
    __syncthreads();

    if (n < N) {
        u64 dpR = 0, dpC = 0;
        #pragma unroll
        for (int s = 0; s < SH; ++s) {
            curR[(size_t)s * N + n] = s * SH_SZ + lds_base[wv][s]     + psR[s] - cr[s];
            curC[(size_t)s * N + n] = s * SH_SZ + lds_base[wv][8 + s] + psC[s] - cc[s];
            dpR |= ((u64)cr[s]) << (8 * s);
            dpC |= ((u64)cc[s]) << (8 * s);
        }
        degpackR[n] = dpR;
        degpackC[n] = dpC;
        off_row[n] = lds_base[wv][16] + psT - tr;
        off_col[n] = lds_base[wv][17] + psU - tc;
        const u64 M27 = (1ULL << 27) - 1;
        const float qs = 1.0f / 65536.0f;
        float sr0 = (float)((TR >> 27) & M27) * qs;
        float sr1 = (float)(TR & M27) * qs;
        float sc0 = (float)((TC >> 27) & M27) * qs;
        float sc1 = (float)(TC & M27) * qs;
        float ir = 1.0f / fmaxf((float)tr, 1.0f);
        float ic = 1.0f / fmaxf((float)tc, 1.0f);
        float* sN = stats + (size_t)n * 8;
        sN[0] = ir;        sN[1] = ic;
        sN[2] = sr0 * ir;  sN[3] = sr1 * ir;
        sN[4] = sc0 * ic;  sN[5] = sc1 * ic;
        sN[6] = (float)tr; sN[7] = (float)tc;
    }
}

// ---------------------------------------------------------------------------
// K3: ATOMIC-FREE sharded fill, 4 edges/thread.
// ---------------------------------------------------------------------------
__global__ __launch_bounds__(256) void k_fill(
    const int* __restrict__ row, const int* __restrict__ col,
    const u8* __restrict__ rankR, const u8* __restrict__ rankC,
    const int* __restrict__ curR, const int* __restrict__ curC,
    int* __restrict__ stageR, int* __restrict__ stageC, int E, int N, int SH_SZ)
{
    int s = blockIdx.x & (SH - 1);
    int j = blockIdx.x >> 3;
    int ebase = s * SH_SZ;
    int ssz = min(SH_SZ, E - ebase);
    int i0 = (j * 256 + threadIdx.x) * 4;
    if (i0 >= ssz) return;
    int e0 = ebase + i0;
    const int* cR = curR + (size_t)s * N;
    const int* cC = curC + (size_t)s * N;
    if (i0 + 4 <= ssz) {
        int4 rr = *(const int4*)(row + e0);
        int4 cc = *(const int4*)(col + e0);
        uchar4 kR = *(const uchar4*)(rankR + e0);
        uchar4 kC = *(const uchar4*)(rankC + e0);
        int aR0 = cR[rr.x], aR1 = cR[rr.y], aR2 = cR[rr.z], aR3 = cR[rr.w];
        int aC0 = cC[cc.x], aC1 = cC[cc.y], aC2 = cC[cc.z], aC3 = cC[cc.w];
        stageR[aR0 + kR.x] = cc.x;
        stageR[aR1 + kR.y] = cc.y;
        stageR[aR2 + kR.z] = cc.z;
        stageR[aR3 + kR.w] = cc.w;
        stageC[aC0 + kC.x] = rr.x;
        stageC[aC1 + kC.y] = rr.y;
        stageC[aC2 + kC.z] = rr.z;
        stageC[aC3 + kC.w] = rr.w;
    } else {
        int m = ssz - i0;
        for (int q = 0; q < m; ++q) {
            int e = e0 + q;
            int r = row[e], c = col[e];
            stageR[cR[r] + rankR[e]] = c;
            stageC[cC[c] + rankC[e]] = r;
        }
    }
}

// ---------------------------------------------------------------------------
// K3.5: compact the 8 sharded segments per node into a true CSR.
// cur = segment START -> src = cur[s] + (k - p[s]).
// ---------------------------------------------------------------------------
__global__ __launch_bounds__(256) void k_reorder(
    const int* __restrict__ stageR, const int* __restrict__ stageC,
    const int* __restrict__ curR, const int* __restrict__ curC,
    const u64* __restrict__ degpackR, const u64* __restrict__ degpackC,
    const int* __restrict__ off_row, const int* __restrict__ off_col,
    int* __restrict__ nbrR, int* __restrict__ nbrC, int N)
{
    int n = blockIdx.x * 4 + (threadIdx.x >> 6);
    if (n >= N) return;
    int lane = threadIdx.x & 63;

    {
        u64 dp = degpackR[n];
        int d[SH], p[SH], st[SH];
        #pragma unroll
        for (int s = 0; s < SH; ++s) d[s] = (int)((dp >> (8 * s)) & 255);
        p[0] = 0;
        #pragma unroll
        for (int s = 1; s < SH; ++s) p[s] = p[s - 1] + d[s - 1];
        int deg = p[SH - 1] + d[SH - 1];
        #pragma unroll
        for (int s = 0; s < SH; ++s)
            st[s] = curR[(size_t)s * N + n] - p[s];
        int base = off_row[n];
        for (int k = lane; k < deg; k += 64) {
            int src = st[0] + k;
            #pragma unroll
            for (int s = 1; s < SH; ++s)
                src = (k >= p[s]) ? st[s] + k : src;
            nbrR[base + k] = stageR[src];
        }
    }
    {
        u64 dp = degpackC[n];
        int d[SH], p[SH], st[SH];
        #pragma unroll
        for (int s = 0; s < SH; ++s) d[s] = (int)((dp >> (8 * s)) & 255);
        p[0] = 0;
        #pragma unroll
        for (int s = 1; s < SH; ++s) p[s] = p[s - 1] + d[s - 1];
        int deg = p[SH - 1] + d[SH - 1];
        #pragma unroll
        for (int s = 0; s < SH; ++s)
            st[s] = curC[(size_t)s * N + n] - p[s];
        int base = off_col[n];
        for (int k = lane; k < deg; k += 64) {
            int src = st[0] + k;
            #pragma unroll
            for (int s = 1; s < SH; ++s)
                src = (k >= p[s]) ? st[s] + k : src;
            nbrC[base + k] = stageC[src];
        }
    }
}

// ---------------------------------------------------------------------------
// K4: fused layer (r12 structure) + software-pipelined index prefetch.
// 512 threads, 16 nodes/block, 2 nodes/wave. Per node: R/C interleaved loop
// (max2 bound, 4 chains). NEW: next batch's 4 indices are issued while the
// current batch's 4 rows are in flight -> steady-state stall ~ row latency
// only (idx latency hidden). No extra predicated waste (bounds unchanged).
// ---------------------------------------------------------------------------
__global__ __launch_bounds__(512) void k_layer(
    const u16* __restrict__ xb,
    const int* __restrict__ off_row, const int* __restrict__ off_col,
    const int* __restrict__ nbrR, const int* __restrict__ nbrC,
    const float* __restrict__ stats,
    const float* __restrict__ Ttw,   // [4][64]
    const float* __restrict__ W,     // [256][64]
    const float* __restrict__ b,     // [64]
    u16* __restrict__ yb, float* __restrict__ yf, int N)
{
    __shared__ float4 hs4[16][32];
    __shared__ float  Ws[128 * 64];

    const uint2* xb2 = (const uint2*)xb;

    int t    = threadIdx.x;
    int lane = t & 63;
    int wv   = t >> 6;
    int c4   = lane & 15;
    int grp  = lane >> 4;
    int base = blockIdx.x * 16;

    float sf[2][4];

    #pragma unroll
    for (int i = 0; i < 2; ++i) {
        int loc = wv * 2 + i;
        int n   = base + loc;
        float4 aR = make_float4(0.f, 0.f, 0.f, 0.f);
        float4 aC = make_float4(0.f, 0.f, 0.f, 0.f);
        float ir = 0.f, ic = 0.f;
        sf[i][0] = sf[i][1] = sf[i][2] = sf[i][3] = 0.f;
        if (n < N) {
            const float4* st = (const float4*)(stats + (size_t)n * 8);
            float4 sA = st[0];
            float4 sB = st[1];
            ir = sA.x; ic = sA.y;
            sf[i][0] = sA.z; sf[i][1] = sA.w;
            sf[i][2] = sB.x; sf[i][3] = sB.y;
            int dR = (int)sB.z, dC = (int)sB.w;
            int sR = off_row[n], sC = off_col[n];
            int m = max(dR, dC);

            // prologue: issue batch-0 indices
            int k0 = grp, k1 = 4 + grp;
            bool pR0 = k0 < dR, pR1 = k1 < dR;
            bool pC0 = k0 < dC, pC1 = k1 < dC;
            int iR0 = nbrR[pR0 ? sR + k0 : 0];
            int iR1 = nbrR[pR1 ? sR + k1 : 0];
            int iC0 = nbrC[pC0 ? sC + k0 : 0];
            int iC1 = nbrC[pC1 ? sC + k1 : 0];

            for (int k = 0; k < m; k += 8) {
                // issue current batch's 4 independent row loads
                uint2 vR0 = xb2[(size_t)iR0 * 16 + c4];
                uint2 vR1 = xb2[(size_t)iR1 * 16 + c4];
                uint2 vC0 = xb2[(size_t)iC0 * 16 + c4];
                uint2 vC1 = xb2[(size_t)iC1 * 16 + c4];
                // prefetch next batch's indices while rows are in flight
                int nk0 = k + 8 + grp, nk1 = k + 12 + grp;
                bool qR0 = nk0 < dR, qR1 = nk1 < dR;
                bool qC0 = nk0 < dC, qC1 = nk1 < dC;
                int jR0 = nbrR[qR0 ? sR + nk0 : 0];
                int jR1 = nbrR[qR1 ? sR + nk1 : 0];
                int jC0 = nbrC[qC0 ? sC + nk0 : 0];
                int jC1 = nbrC[qC1 ? sC + nk1 : 0];
                // accumulate current rows
                if (pR0) {
                    aR.x += uaf(vR0.x << 16); aR.y += uaf(vR0.x & 0xffff0000u);
                    aR.z += uaf(vR0.y << 16); aR.w += uaf(vR0.y & 0xffff0000u);
                }
                if (pR1) {
                    aR.x += uaf(vR1.x << 16); aR.y += uaf(vR1.x & 0xffff0000u);
                    aR.z += uaf(vR1.y << 16); aR.w += uaf(vR1.y & 0xffff0000u);
                }
                if (pC0) {
                    aC.x += uaf(vC0.x << 16); aC.y += uaf(vC0.x & 0xffff0000u);
                    aC.z += uaf(vC0.y << 16); aC.w += uaf(vC0.y & 0xffff0000u);
                }
                if (pC1) {
                    aC.x += uaf(vC1.x << 16); aC.y += uaf(vC1.x & 0xffff0000u);
                    aC.z += uaf(vC1.y << 16); aC.w += uaf(vC1.y & 0xffff0000u);
                }
                // rotate prefetched batch into place
                iR0 = jR0; iR1 = jR1; iC0 = jC0; iC1 = jC1;
                pR0 = qR0; pR1 = qR1; pC0 = qC0; pC1 = qC1;
            }
        }
        #pragma unroll
        for (int o = 16; o < 64; o <<= 1) {
            aR.x += __shfl_xor(aR.x, o); aR.y += __shfl_xor(aR.y, o);
            aR.z += __shfl_xor(aR.z, o); aR.w += __shfl_xor(aR.w, o);
            aC.x += __shfl_xor(aC.x, o); aC.y += __shfl_xor(aC.y, o);
            aC.z += __shfl_xor(aC.z, o); aC.w += __shfl_xor(aC.w, o);
        }
        if (grp == 0) {
            hs4[loc][c4]      = make_float4(aR.x * ir, aR.y * ir, aR.z * ir, aR.w * ir);
            hs4[loc][16 + c4] = make_float4(aC.x * ic, aC.y * ic, aC.z * ic, aC.w * ic);
        }
    }

    __syncthreads();
    #pragma unroll
    for (int i = 0; i < 16; ++i) {
        int L = i * 512 + t;
        Ws[L] = W[L + ((L < 4096) ? 0 : 4096)];
    }
    __syncthreads();

    const float* hsf = (const float*)hs4;
    int r0 = (wv * 2) * 128, r1 = r0 + 128;
    float a0 = 0.f, a1 = 0.f;
    #pragma unroll 8
    for (int j = 0; j < 128; ++j) {
        float wj = Ws[j * 64 + lane];
        a0 += hsf[r0 + j] * wj;
        a1 += hsf[r1 + j] * wj;
    }

    float tR0 = Ttw[lane],       tR1 = Ttw[64 + lane];
    float tC0 = Ttw[128 + lane], tC1 = Ttw[192 + lane];
    float bias = b[lane];
    float vv[2] = {a0, a1};
    #pragma unroll
    for (int i = 0; i < 2; ++i) {
        int n = base + wv * 2 + i;
        if (n < N) {
            float v = vv[i] + sf[i][0] * tR0 + sf[i][1] * tR1
                            + sf[i][2] * tC0 + sf[i][3] * tC1 + bias;
            v = fmaxf(v, 0.0f);
            if (yf) {
                yf[(size_t)n * D + lane] = v;
            } else {
                unsigned u = __float_as_uint(v);
                yb[(size_t)n * D + lane] = (u16)((u + 0x7fffu + ((u >> 16) & 1u)) >> 16);
            }
        }
    }
}

// ---------------------------------------------------------------------------
extern "C" void kernel_launch(void* const* d_in, const int* in_sizes, int n_in,
                              void* d_out, int out_size, void* d_ws, size_t ws_size,
                              hipStream_t stream)
{
    const float* X   = (const float*)d_in[0];
    const int*   ei  = (const int*)  d_in[1];
    const float* el  = (const float*)d_in[2];
    const float* w1  = (const float*)d_in[3];
    const float* tw1 = (const float*)d_in[4];
    const float* b1  = (const float*)d_in[5];
    const float* w2  = (const float*)d_in[6];
    const float* tw2 = (const float*)d_in[7];
    const float* b2  = (const float*)d_in[8];
    float* out = (float*)d_out;

    int N = in_sizes[0] / D;     // 50000
    int E = in_sizes[1] / 2;     // 800000
    const int* row = ei;
    const int* col = ei + E;
    int SH_SZ = (((E + SH - 1) / SH) + 3) & ~3;   // multiple of 4 for int4 loads

    // Workspace (~25.6 MiB). pack -> stage CSR -> h1 bf16 share a region.
    size_t packBytes = (size_t)2 * SH * N * sizeof(u64);
    size_t stageBytes = (size_t)2 * (size_t)SH * SH_SZ * sizeof(int);
    size_t h1Bytes = (size_t)64 * N * sizeof(u16);
    if (stageBytes > packBytes) packBytes = stageBytes;
    if (h1Bytes > packBytes) packBytes = h1Bytes;

    char* wsb = (char*)d_ws;
    u64*   packR    = (u64*)wsb;                        // SH*N u64 (zeroed)
    u64*   packC    = packR + (size_t)SH * N;           // SH*N u64 (zeroed)
    int*   stageR   = (int*)wsb;                        // SH*SH_SZ ints (aliases pack)
    int*   stageC   = stageR + (size_t)SH * SH_SZ;      // SH*SH_SZ ints
    u16*   h1b      = (u16*)wsb;                        // 64N bf16 (aliases stage)
    int*   gcur     = (int*)(wsb + packBytes);          // 1024 ints line-padded (zeroed)
    int*   curR     = gcur + 1024;                      // SH*N
    int*   curC     = curR + (size_t)SH * N;            // SH*N
    u64*   degpackR = (u64*)(curC + (size_t)SH * N);    // N
    u64*   degpackC = degpackR + N;                     // N
    int*   off_row  = (int*)(degpackC + N);             // N
    int*   off_col  = off_row + N;                      // N
    float* stats    = (float*)(off_col + N);            // 8N
    float* Ttw1     = stats + (size_t)8 * N;            // 256
    float* Ttw2     = Ttw1 + 256;                       // 256
    int*   nbrR     = (int*)(Ttw2 + 256);               // E
    int*   nbrC     = nbrR + E;                         // E
    u16*   Xb       = (u16*)(nbrC + E);                 // 64N bf16
    u8*    rankR    = (u8*)(Xb + (size_t)64 * N);       // E
    u8*    rankC    = rankR + E;                        // E

    (void)hipMemsetAsync(packR, 0, (size_t)2 * SH * N * sizeof(u64), stream);
    (void)hipMemsetAsync(gcur, 0, 1024 * sizeof(int), stream);

    k_cvt<<<(N * 8 + 255) / 256, 256, 0, stream>>>((const float4*)X, (uint4*)Xb, N * 8);
    k_ttw<<<2, 256, 0, stream>>>(tw1, w1, Ttw1, tw2, w2, Ttw2);

    int SB4 = SH * ((SH_SZ + 1023) / 1024);
    int NB = (N + 255) / 256;
    int RB = (N + 3) / 4;
    int LB = (N + 15) / 16;

    k_count<<<SB4, 256, 0, stream>>>(row, col, el, packR, packC,
                                     rankR, rankC, E, N, SH_SZ);
    k_prep<<<NB, 256, 0, stream>>>(packR, packC, curR, curC,
                                   degpackR, degpackC, off_row, off_col,
                                   stats, gcur, N, SH_SZ);
    k_fill<<<SB4, 256, 0, stream>>>(row, col, rankR, rankC, curR, curC,
                                    stageR, stageC, E, N, SH_SZ);
    k_reorder<<<RB, 256, 0, stream>>>(stageR, stageC, curR, curC,
                                      degpackR, degpackC, off_row, off_col,
                                      nbrR, nbrC, N);

    // layer 1: Xb -> h1b (bf16, aliases dead stage region); layer 2 -> out f32
    k_layer<<<LB, 512, 0, stream>>>(Xb, off_row, off_col, nbrR, nbrC, stats,
                                    Ttw1, w1, b1, h1b, nullptr, N);
    k_layer<<<LB, 512, 0, stream>>>(h1b, off_row, off_col, nbrR, nbrC, stats,
                                    Ttw2, w2, b2, nullptr, out, N);
}